// Round 11
// baseline (48.831 us; speedup 1.0000x reference)
//
#include <hip/hip_runtime.h>
#include <math.h>

#define DDIM 512
#define BT 64           // block tile (M and N), one wave per block
#define NT 64           // N / BT tile grid dimension
#define NTILES (NT * (NT + 1) / 2)   // 2080 triangular tiles (divisible by 8)
#define NSL 16          // K slices of 32 (DDIM/32)
#define NCH 64          // 64-wide column chunks for partials

typedef __attribute__((ext_vector_type(4))) float f32x4;

// ---------- OCP e4m3fn scalar convert (RNE), no header dependency ----------
__device__ __forceinline__ unsigned char f2e4m3(float x) {
  unsigned ux = __builtin_bit_cast(unsigned, x);
  unsigned sign = (ux >> 24) & 0x80u;
  float a = fminf(fabsf(x), 448.f);
  unsigned ua = __builtin_bit_cast(unsigned, a);
  int E = (int)((ua >> 23) & 0xff);
  if (E == 0) return (unsigned char)sign;            // 0 / f32-denormal -> 0
  E -= 127;
  int t = E - 3; if (t < -9) t = -9;                 // grid = 2^t
  float c = __builtin_bit_cast(float, (unsigned)((t + 150) << 23));  // 2^(23+t)
  float r = (a + c) - c;                             // RNE to e4m3 grid
  if (r <= 0.f) return (unsigned char)sign;
  unsigned ur = __builtin_bit_cast(unsigned, r);
  int Er = (int)((ur >> 23) & 0xff) - 127;
  if (Er < -6) {                                     // subnormal: man * 2^-9
    unsigned man = (unsigned)(r * 512.f + 0.5f);
    return (unsigned char)(sign | man);
  }
  unsigned man = (ur >> 20) & 7u;
  return (unsigned char)(sign | ((unsigned)(Er + 7) << 3) | man);
}
__device__ __forceinline__ float e4m32f(unsigned char b) {
  int e = (b >> 3) & 0xf, m = b & 7;
  float v = (e == 0) ? (float)m * 0.001953125f
                     : (float)(8 + m) * __builtin_bit_cast(float, (unsigned)((e + 117) << 23));
  return (b & 0x80) ? -v : v;
}

// fragment-major: frag (rt, s) = rows rt*16..+15, k = s*32..+31.
// lane (g<<4)|cl holds row rt*16+cl, k bytes s*32+g*8..+7  -> 8 B/lane, 512 B/frag.
__device__ __forceinline__ size_t frag_off(int rt, int s, int lane) {
  return ((size_t)(rt * NSL + s) * 64 + lane) * 8;   // byte offset
}

// ---- kernel 1: normalize rows w and w+B to fp8 frag layout, pos[w] ---------
__global__ void k_prep(const float* __restrict__ zi, const float* __restrict__ zj,
                       const float* __restrict__ tempp,
                       unsigned char* __restrict__ zf, float* __restrict__ pos,
                       int B) {
  int wv = (blockIdx.x * blockDim.x + threadIdx.x) >> 6;
  int lane = threadIdx.x & 63;
  if (wv >= B) return;
  const float* a = zi + (size_t)wv * DDIM;
  const float* b = zj + (size_t)wv * DDIM;
  float4 a0 = *(const float4*)(a + lane * 8);
  float4 a1 = *(const float4*)(a + lane * 8 + 4);
  float4 b0 = *(const float4*)(b + lane * 8);
  float4 b1 = *(const float4*)(b + lane * 8 + 4);
  float av[8] = {a0.x, a0.y, a0.z, a0.w, a1.x, a1.y, a1.z, a1.w};
  float bv[8] = {b0.x, b0.y, b0.z, b0.w, b1.x, b1.y, b1.z, b1.w};
  float sa = 0.f, sb = 0.f;
#pragma unroll
  for (int i = 0; i < 8; ++i) { sa = fmaf(av[i], av[i], sa); sb = fmaf(bv[i], bv[i], sb); }
#pragma unroll
  for (int off = 32; off; off >>= 1) { sa += __shfl_xor(sa, off, 64); sb += __shfl_xor(sb, off, 64); }
  float ia = 1.f / fmaxf(sqrtf(sa), 1e-8f);
  float ib = 1.f / fmaxf(sqrtf(sb), 1e-8f);
  unsigned long long pa = 0ull, pb = 0ull;
  float fa[8], fb[8];
#pragma unroll
  for (int i = 0; i < 8; ++i) {
    unsigned char qa = f2e4m3(av[i] * ia); fa[i] = e4m32f(qa);
    unsigned char qb = f2e4m3(bv[i] * ib); fb[i] = e4m32f(qb);
    pa |= ((unsigned long long)qa) << (8 * i);
    pb |= ((unsigned long long)qb) << (8 * i);
  }
  // lane covers k = lane*8..+7 -> slice s = lane>>2, sub g = lane&3
  const int s = lane >> 2, g = lane & 3;
  {
    int r = wv;
    *(unsigned long long*)(zf + frag_off(r >> 4, s, (g << 4) | (r & 15))) = pa;
    r = wv + B;
    *(unsigned long long*)(zf + frag_off(r >> 4, s, (g << 4) | (r & 15))) = pb;
  }
  float pd = 0.f;
#pragma unroll
  for (int i = 0; i < 8; ++i) pd = fmaf(fa[i], fb[i], pd);
#pragma unroll
  for (int off = 32; off; off >>= 1) pd += __shfl_xor(pd, off, 64);
  if (lane == 0) {
    float p = pd / tempp[0];
    pos[wv] = p; pos[wv + B] = p;
  }
}

// ---- kernel 2: one wave per 64x64 tile, fp8 MFMA, barrier/LDS-free ---------
__global__ __launch_bounds__(64) void k_main(
    const unsigned char* __restrict__ zf, const float* __restrict__ pos,
    const float* __restrict__ tempp, float* __restrict__ partS,
    float* __restrict__ partC, int B) {
  // XCD-aware bijective swizzle (2080 = 8 * 260)
  int tri = (blockIdx.x & 7) * (NTILES / 8) + (blockIdx.x >> 3);
  int bi = 0;
  while (tri >= NT - bi) { tri -= NT - bi; ++bi; }
  const int bj = bi + tri;
  const int r0 = bi * BT, c0 = bj * BT;
  const bool diag = (bi == bj);
  const float invt = 1.0f / tempp[0];

  const int lane = threadIdx.x;
  const int cl = lane & 15, g = lane >> 4;
  const int art = r0 >> 4;                   // 4 A row-tiles
  const int brt = c0 >> 4;                   // 4 B col-tiles

  f32x4 acc[4][4];
#pragma unroll
  for (int m = 0; m < 4; ++m)
#pragma unroll
    for (int n = 0; n < 4; ++n) acc[m][n] = (f32x4){0.f, 0.f, 0.f, 0.f};

#pragma unroll 4
  for (int s = 0; s < NSL; ++s) {            // 16 k-slices, no LDS, no barriers
    long long aF[4], bF[4];
#pragma unroll
    for (int m = 0; m < 4; ++m)
      aF[m] = *(const long long*)(zf + frag_off(art + m, s, lane));
#pragma unroll
    for (int n = 0; n < 4; ++n)
      bF[n] = *(const long long*)(zf + frag_off(brt + n, s, lane));
#pragma unroll
    for (int m = 0; m < 4; ++m)
#pragma unroll
      for (int n = 0; n < 4; ++n)
        acc[m][n] = __builtin_amdgcn_mfma_f32_16x16x32_fp8_fp8(aF[m], bF[n], acc[m][n], 0, 0, 0);
  }

  // ---- epilogue: fused exp-sum / rank-count, both directions ----
  int growv[16], gpartr[16];
  float pvr[16];
#pragma unroll
  for (int m = 0; m < 4; ++m)
#pragma unroll
    for (int reg = 0; reg < 4; ++reg) {
      int idx = m * 4 + reg;
      int grow = r0 + m * 16 + g * 4 + reg;
      growv[idx] = grow;
      gpartr[idx] = (grow < B) ? grow + B : grow - B;
      pvr[idx] = pos[grow];
    }
  int gcolv[4], gpartc[4];
  float pvc[4];
#pragma unroll
  for (int n = 0; n < 4; ++n) {
    int gcol = c0 + n * 16 + cl;
    gcolv[n] = gcol;
    gpartc[n] = (gcol < B) ? gcol + B : gcol - B;
    pvc[n] = pos[gcol];
  }

  float ssr[16], ccr[16], ssc[4], ccc[4];
#pragma unroll
  for (int i = 0; i < 16; ++i) { ssr[i] = 0.f; ccr[i] = 0.f; }
#pragma unroll
  for (int n = 0; n < 4; ++n) { ssc[n] = 0.f; ccc[n] = 0.f; }

#pragma unroll
  for (int m = 0; m < 4; ++m)
#pragma unroll
    for (int n = 0; n < 4; ++n)
#pragma unroll
      for (int reg = 0; reg < 4; ++reg) {
        const int idx = m * 4 + reg;
        float val = acc[m][n][reg] * invt;
        float e = __expf(val);
        bool isd = diag && (gcolv[n] == growv[idx]);
        if (!isd) {
          ssr[idx] += e;
          ccr[idx] += (gcolv[n] != gpartr[idx] && val > pvr[idx]) ? 1.f : 0.f;
        }
        if (!diag) {
          ssc[n] += e;
          ccc[n] += (growv[idx] != gpartc[n] && val > pvc[n]) ? 1.f : 0.f;
        }
      }

  // row partials: reduce over cl (lane bits 0-3), write chunk bj
#pragma unroll
  for (int idx = 0; idx < 16; ++idx) {
    float s = ssr[idx], c = ccr[idx];
#pragma unroll
    for (int off = 1; off < 16; off <<= 1) {
      s += __shfl_xor(s, off, 64);
      c += __shfl_xor(c, off, 64);
    }
    if (cl == 0) {
      partS[(size_t)growv[idx] * NCH + bj] = s;
      partC[(size_t)growv[idx] * NCH + bj] = c;
    }
  }
  // col partials: reduce over g (lane bits 4-5), write chunk bi
  if (!diag) {
#pragma unroll
    for (int n = 0; n < 4; ++n) {
      float s = ssc[n], c = ccc[n];
      s += __shfl_xor(s, 16, 64); c += __shfl_xor(c, 16, 64);
      s += __shfl_xor(s, 32, 64); c += __shfl_xor(c, 32, 64);
      if (g == 0) {
        partS[(size_t)gcolv[n] * NCH + bi] = s;
        partC[(size_t)gcolv[n] * NCH + bi] = c;
      }
    }
  }
}

// ---- kernel 3: per-row combine of 64 chunks -> rowLoss, rowCnt ----
__global__ void k_rowfin(const float* __restrict__ partS, const float* __restrict__ partC,
                         const float* __restrict__ pos, float* __restrict__ rowL,
                         float* __restrict__ rowC, int N) {
  int r = (blockIdx.x * blockDim.x + threadIdx.x) >> 6;
  int lane = threadIdx.x & 63;
  if (r >= N) return;
  float s = partS[(size_t)r * NCH + lane];
  float c = partC[(size_t)r * NCH + lane];
#pragma unroll
  for (int off = 32; off; off >>= 1) { s += __shfl_xor(s, off, 64); c += __shfl_xor(c, off, 64); }
  if (lane == 0) {
    rowL[r] = logf(s) - pos[r];
    rowC[r] = c;
  }
}

// ---- kernel 4: final reduction to (loss, avg_rank) ----
__global__ void k_final(const float* __restrict__ rowL, const float* __restrict__ rowC,
                        float* __restrict__ out, int N) {
  float ls = 0.f, cs = 0.f;
  for (int r = threadIdx.x; r < N; r += 256) { ls += rowL[r]; cs += rowC[r]; }
  __shared__ float l[256], c[256];
  l[threadIdx.x] = ls; c[threadIdx.x] = cs;
  __syncthreads();
  for (int off = 128; off; off >>= 1) {
    if (threadIdx.x < off) { l[threadIdx.x] += l[threadIdx.x + off]; c[threadIdx.x] += c[threadIdx.x + off]; }
    __syncthreads();
  }
  if (threadIdx.x == 0) { out[0] = l[0] / (float)N; out[1] = c[0] / (float)N; }
}

extern "C" void kernel_launch(void* const* d_in, const int* in_sizes, int n_in,
                              void* d_out, int out_size, void* d_ws, size_t ws_size,
                              hipStream_t stream) {
  const float* zi = (const float*)d_in[0];
  const float* zj = (const float*)d_in[1];
  const float* temp = (const float*)d_in[2];
  float* out = (float*)d_out;

  const int B = in_sizes[0] / DDIM;   // 2048
  const int N = 2 * B;                // 4096

  unsigned char* zf = (unsigned char*)d_ws;             // N*DDIM fp8 = 2 MB, frag-major
  float* fws = (float*)(zf + (size_t)N * DDIM);
  float* pos   = fws;                                    // N
  float* partS = pos + N;                                // N*NCH = 1 MB
  float* partC = partS + (size_t)N * NCH;                // N*NCH = 1 MB
  float* rowL  = partC + (size_t)N * NCH;                // N
  float* rowC  = rowL + N;                               // N

  k_prep<<<(B * 64) / 256, 256, 0, stream>>>(zi, zj, temp, zf, pos, B);
  k_main<<<NTILES, 64, 0, stream>>>(zf, pos, temp, partS, partC, B);
  k_rowfin<<<(N * 64) / 256, 256, 0, stream>>>(partS, partC, pos, rowL, rowC, N);
  k_final<<<1, 256, 0, stream>>>(rowL, rowC, out, N);
}

// Round 12
// 48.253 us; speedup vs baseline: 1.0120x; 1.0120x over previous
//
#include <hip/hip_runtime.h>
#include <math.h>

#define DDIM 512
#define BT 64           // block tile (M and N); 4 waves x 16 rows each
#define NT 64           // N / BT tile grid dimension
#define NTILES (NT * (NT + 1) / 2)   // 2080 triangular tiles (divisible by 8)
#define NSL 16          // K slices of 32 (DDIM/32)
#define NCH 64          // 64-wide column chunks for partials

typedef __attribute__((ext_vector_type(4))) float f32x4;

// ---------- OCP e4m3fn scalar convert (RNE), no header dependency ----------
__device__ __forceinline__ unsigned char f2e4m3(float x) {
  unsigned ux = __builtin_bit_cast(unsigned, x);
  unsigned sign = (ux >> 24) & 0x80u;
  float a = fminf(fabsf(x), 448.f);
  unsigned ua = __builtin_bit_cast(unsigned, a);
  int E = (int)((ua >> 23) & 0xff);
  if (E == 0) return (unsigned char)sign;            // 0 / f32-denormal -> 0
  E -= 127;
  int t = E - 3; if (t < -9) t = -9;                 // grid = 2^t
  float c = __builtin_bit_cast(float, (unsigned)((t + 150) << 23));  // 2^(23+t)
  float r = (a + c) - c;                             // RNE to e4m3 grid
  if (r <= 0.f) return (unsigned char)sign;
  unsigned ur = __builtin_bit_cast(unsigned, r);
  int Er = (int)((ur >> 23) & 0xff) - 127;
  if (Er < -6) {                                     // subnormal: man * 2^-9
    unsigned man = (unsigned)(r * 512.f + 0.5f);
    return (unsigned char)(sign | man);
  }
  unsigned man = (ur >> 20) & 7u;
  return (unsigned char)(sign | ((unsigned)(Er + 7) << 3) | man);
}
__device__ __forceinline__ float e4m32f(unsigned char b) {
  int e = (b >> 3) & 0xf, m = b & 7;
  float v = (e == 0) ? (float)m * 0.001953125f
                     : (float)(8 + m) * __builtin_bit_cast(float, (unsigned)((e + 117) << 23));
  return (b & 0x80) ? -v : v;
}

// fragment-major: frag (rt, s) = rows rt*16..+15, k = s*32..+31.
// lane (g<<4)|cl holds row rt*16+cl, k bytes s*32+g*8..+7 -> 8 B/lane, 512 B/frag.
__device__ __forceinline__ size_t frag_off(int rt, int s, int lane) {
  return ((size_t)(rt * NSL + s) * 64 + lane) * 8;   // byte offset
}

// ---- kernel 1: normalize rows w and w+B to fp8 frag layout, pos[w] ---------
__global__ void k_prep(const float* __restrict__ zi, const float* __restrict__ zj,
                       const float* __restrict__ tempp,
                       unsigned char* __restrict__ zf, float* __restrict__ pos,
                       int B) {
  int wv = (blockIdx.x * blockDim.x + threadIdx.x) >> 6;
  int lane = threadIdx.x & 63;
  if (wv >= B) return;
  const float* a = zi + (size_t)wv * DDIM;
  const float* b = zj + (size_t)wv * DDIM;
  float4 a0 = *(const float4*)(a + lane * 8);
  float4 a1 = *(const float4*)(a + lane * 8 + 4);
  float4 b0 = *(const float4*)(b + lane * 8);
  float4 b1 = *(const float4*)(b + lane * 8 + 4);
  float av[8] = {a0.x, a0.y, a0.z, a0.w, a1.x, a1.y, a1.z, a1.w};
  float bv[8] = {b0.x, b0.y, b0.z, b0.w, b1.x, b1.y, b1.z, b1.w};
  float sa = 0.f, sb = 0.f;
#pragma unroll
  for (int i = 0; i < 8; ++i) { sa = fmaf(av[i], av[i], sa); sb = fmaf(bv[i], bv[i], sb); }
#pragma unroll
  for (int off = 32; off; off >>= 1) { sa += __shfl_xor(sa, off, 64); sb += __shfl_xor(sb, off, 64); }
  float ia = 1.f / fmaxf(sqrtf(sa), 1e-8f);
  float ib = 1.f / fmaxf(sqrtf(sb), 1e-8f);
  unsigned long long pa = 0ull, pb = 0ull;
  float fa[8], fb[8];
#pragma unroll
  for (int i = 0; i < 8; ++i) {
    unsigned char qa = f2e4m3(av[i] * ia); fa[i] = e4m32f(qa);
    unsigned char qb = f2e4m3(bv[i] * ib); fb[i] = e4m32f(qb);
    pa |= ((unsigned long long)qa) << (8 * i);
    pb |= ((unsigned long long)qb) << (8 * i);
  }
  // lane covers k = lane*8..+7 -> slice s = lane>>2, sub g = lane&3
  const int s = lane >> 2, g = lane & 3;
  {
    int r = wv;
    *(unsigned long long*)(zf + frag_off(r >> 4, s, (g << 4) | (r & 15))) = pa;
    r = wv + B;
    *(unsigned long long*)(zf + frag_off(r >> 4, s, (g << 4) | (r & 15))) = pb;
  }
  float pd = 0.f;
#pragma unroll
  for (int i = 0; i < 8; ++i) pd = fmaf(fa[i], fb[i], pd);
#pragma unroll
  for (int off = 32; off; off >>= 1) pd += __shfl_xor(pd, off, 64);
  if (lane == 0) {
    float p = pd / tempp[0];
    pos[wv] = p; pos[wv + B] = p;
  }
}

// ---- kernel 2: 4 waves x 16-row tiles, fp8 MFMA, barrier-free main loop ----
__global__ __launch_bounds__(256) void k_main(
    const unsigned char* __restrict__ zf, const float* __restrict__ pos,
    const float* __restrict__ tempp, float* __restrict__ partS,
    float* __restrict__ partC, int B) {
  // XCD-aware bijective swizzle (2080 = 8 * 260)
  int tri = (blockIdx.x & 7) * (NTILES / 8) + (blockIdx.x >> 3);
  int bi = 0;
  while (tri >= NT - bi) { tri -= NT - bi; ++bi; }
  const int bj = bi + tri;
  const int r0 = bi * BT, c0 = bj * BT;
  const bool diag = (bi == bj);
  const float invt = 1.0f / tempp[0];

  const int t = threadIdx.x;
  const int lane = t & 63;
  const int wave = t >> 6;                   // wave owns rows r0+wave*16..+15
  const int cl = lane & 15, g = lane >> 4;
  const int art = (r0 >> 4) + wave;          // wave's A row-tile
  const int brt = c0 >> 4;                   // block's 4 B col-tiles

  f32x4 acc[4];
#pragma unroll
  for (int n = 0; n < 4; ++n) acc[n] = (f32x4){0.f, 0.f, 0.f, 0.f};

#pragma unroll 2
  for (int s = 0; s < NSL; ++s) {            // 16 k-slices, no LDS, no barriers
    long long aF = *(const long long*)(zf + frag_off(art, s, lane));
    long long bF[4];
#pragma unroll
    for (int n = 0; n < 4; ++n)
      bF[n] = *(const long long*)(zf + frag_off(brt + n, s, lane));
#pragma unroll
    for (int n = 0; n < 4; ++n)
      acc[n] = __builtin_amdgcn_mfma_f32_16x16x32_fp8_fp8(aF, bF[n], acc[n], 0, 0, 0);
  }

  // ---- epilogue: fused exp-sum / rank-count, both directions ----
  int growv[4], gpartr[4];
  float pvr[4];
#pragma unroll
  for (int reg = 0; reg < 4; ++reg) {
    int grow = r0 + wave * 16 + g * 4 + reg;
    growv[reg] = grow;
    gpartr[reg] = (grow < B) ? grow + B : grow - B;
    pvr[reg] = pos[grow];
  }
  int gcolv[4], gpartc[4];
  float pvc[4];
#pragma unroll
  for (int n = 0; n < 4; ++n) {
    int gcol = c0 + n * 16 + cl;
    gcolv[n] = gcol;
    gpartc[n] = (gcol < B) ? gcol + B : gcol - B;
    pvc[n] = pos[gcol];
  }

  float ssr[4], ccr[4], ssc[4], ccc[4];
#pragma unroll
  for (int i = 0; i < 4; ++i) { ssr[i] = 0.f; ccr[i] = 0.f; ssc[i] = 0.f; ccc[i] = 0.f; }

#pragma unroll
  for (int n = 0; n < 4; ++n)
#pragma unroll
    for (int reg = 0; reg < 4; ++reg) {
      float val = acc[n][reg] * invt;
      float e = __expf(val);
      bool isd = diag && (gcolv[n] == growv[reg]);
      if (!isd) {
        ssr[reg] += e;
        ccr[reg] += (gcolv[n] != gpartr[reg] && val > pvr[reg]) ? 1.f : 0.f;
      }
      if (!diag) {
        ssc[n] += e;
        ccc[n] += (growv[reg] != gpartc[n] && val > pvc[n]) ? 1.f : 0.f;
      }
    }

  // row partials: each wave owns complete rows -> reduce over cl only
#pragma unroll
  for (int reg = 0; reg < 4; ++reg) {
    float s = ssr[reg], c = ccr[reg];
#pragma unroll
    for (int off = 1; off < 16; off <<= 1) {
      s += __shfl_xor(s, off, 64);
      c += __shfl_xor(c, off, 64);
    }
    if (cl == 0) {
      partS[(size_t)growv[reg] * NCH + bj] = s;
      partC[(size_t)growv[reg] * NCH + bj] = c;
    }
  }

  // col partials: reduce over g in-wave, then cross-wave combine via LDS
  __shared__ float colS[256], colC[256];      // [4 waves][64 cols]
  if (!diag) {
#pragma unroll
    for (int n = 0; n < 4; ++n) {
      ssc[n] += __shfl_xor(ssc[n], 16, 64); ccc[n] += __shfl_xor(ccc[n], 16, 64);
      ssc[n] += __shfl_xor(ssc[n], 32, 64); ccc[n] += __shfl_xor(ccc[n], 32, 64);
    }
    if (g == 0) {
#pragma unroll
      for (int n = 0; n < 4; ++n) {
        colS[wave * 64 + n * 16 + cl] = ssc[n];
        colC[wave * 64 + n * 16 + cl] = ccc[n];
      }
    }
  }
  __syncthreads();
  if (!diag && t < 64) {
    float s = colS[t] + colS[64 + t] + colS[128 + t] + colS[192 + t];
    float c = colC[t] + colC[64 + t] + colC[128 + t] + colC[192 + t];
    partS[(size_t)(c0 + t) * NCH + bi] = s;
    partC[(size_t)(c0 + t) * NCH + bi] = c;
  }
}

// ---- kernel 3: per-row combine of 64 chunks -> rowLoss, rowCnt ----
__global__ void k_rowfin(const float* __restrict__ partS, const float* __restrict__ partC,
                         const float* __restrict__ pos, float* __restrict__ rowL,
                         float* __restrict__ rowC, int N) {
  int r = (blockIdx.x * blockDim.x + threadIdx.x) >> 6;
  int lane = threadIdx.x & 63;
  if (r >= N) return;
  float s = partS[(size_t)r * NCH + lane];
  float c = partC[(size_t)r * NCH + lane];
#pragma unroll
  for (int off = 32; off; off >>= 1) { s += __shfl_xor(s, off, 64); c += __shfl_xor(c, off, 64); }
  if (lane == 0) {
    rowL[r] = logf(s) - pos[r];
    rowC[r] = c;
  }
}

// ---- kernel 4: final reduction to (loss, avg_rank) ----
__global__ void k_final(const float* __restrict__ rowL, const float* __restrict__ rowC,
                        float* __restrict__ out, int N) {
  float ls = 0.f, cs = 0.f;
  for (int r = threadIdx.x; r < N; r += 256) { ls += rowL[r]; cs += rowC[r]; }
  __shared__ float l[256], c[256];
  l[threadIdx.x] = ls; c[threadIdx.x] = cs;
  __syncthreads();
  for (int off = 128; off; off >>= 1) {
    if (threadIdx.x < off) { l[threadIdx.x] += l[threadIdx.x + off]; c[threadIdx.x] += c[threadIdx.x + off]; }
    __syncthreads();
  }
  if (threadIdx.x == 0) { out[0] = l[0] / (float)N; out[1] = c[0] / (float)N; }
}

extern "C" void kernel_launch(void* const* d_in, const int* in_sizes, int n_in,
                              void* d_out, int out_size, void* d_ws, size_t ws_size,
                              hipStream_t stream) {
  const float* zi = (const float*)d_in[0];
  const float* zj = (const float*)d_in[1];
  const float* temp = (const float*)d_in[2];
  float* out = (float*)d_out;

  const int B = in_sizes[0] / DDIM;   // 2048
  const int N = 2 * B;                // 4096

  unsigned char* zf = (unsigned char*)d_ws;             // N*DDIM fp8 = 2 MB, frag-major
  float* fws = (float*)(zf + (size_t)N * DDIM);
  float* pos   = fws;                                    // N
  float* partS = pos + N;                                // N*NCH = 1 MB
  float* partC = partS + (size_t)N * NCH;                // N*NCH = 1 MB
  float* rowL  = partC + (size_t)N * NCH;                // N
  float* rowC  = rowL + N;                               // N

  k_prep<<<(B * 64) / 256, 256, 0, stream>>>(zi, zj, temp, zf, pos, B);
  k_main<<<NTILES, 256, 0, stream>>>(zf, pos, temp, partS, partC, B);
  k_rowfin<<<(N * 64) / 256, 256, 0, stream>>>(partS, partC, pos, rowL, rowC, N);
  k_final<<<1, 256, 0, stream>>>(rowL, rowC, out, N);
}